// Round 1
// baseline (352.645 us; speedup 1.0000x reference)
//
#include <hip/hip_runtime.h>

#define CC 128          // channels
#define BSEG 16         // segments
#define EPSV 1e-5f
#define ROWS_PER_BLOCK 512

// ---------------------------------------------------------------------------
// Kernel 1: per-segment per-channel sum / sumsq / count.
// Block owns ROWS_PER_BLOCK contiguous rows. Thread layout: 8 row-lanes x 32
// channel-quads (float4). batch_idx is sorted, so nearly all blocks are
// segment-uniform -> LDS reduce + 256 atomics/block. Boundary blocks (rare)
// take a flush-on-change per-thread atomic path.
// ---------------------------------------------------------------------------
__global__ __launch_bounds__(256) void ms_stats(const float* __restrict__ x,
                                                const int* __restrict__ bidx,
                                                int n,
                                                float* __restrict__ sum,
                                                float* __restrict__ sumsq,
                                                float* __restrict__ cnt)
{
    const int r0 = blockIdx.x * ROWS_PER_BLOCK;
    if (r0 >= n) return;
    const int rend = min(r0 + ROWS_PER_BLOCK, n);
    const int tq = threadIdx.x & 31;   // channel quad 0..31 -> channels 4*tq..4*tq+3
    const int tr = threadIdx.x >> 5;   // row lane 0..7

    const int seg_first = bidx[r0];
    const int seg_last  = bidx[rend - 1];

    float s0 = 0.f, s1 = 0.f, s2 = 0.f, s3 = 0.f;
    float q0 = 0.f, q1 = 0.f, q2 = 0.f, q3 = 0.f;

    if (seg_first == seg_last) {
        // Uniform block (common case).
        for (int r = r0 + tr; r < rend; r += 8) {
            const float4 v = *reinterpret_cast<const float4*>(x + (size_t)r * CC + tq * 4);
            s0 += v.x; s1 += v.y; s2 += v.z; s3 += v.w;
            q0 += v.x * v.x; q1 += v.y * v.y; q2 += v.z * v.z; q3 += v.w * v.w;
        }
        // Reduce the 8 row-lanes in LDS. Layout [tr][slot][tq]: lane-consecutive
        // on both write and read -> conflict-free.
        __shared__ float red[8][8][32];
        red[tr][0][tq] = s0; red[tr][1][tq] = s1; red[tr][2][tq] = s2; red[tr][3][tq] = s3;
        red[tr][4][tq] = q0; red[tr][5][tq] = q1; red[tr][6][tq] = q2; red[tr][7][tq] = q3;
        __syncthreads();
        const int j = threadIdx.x >> 5;   // slot 0..7 (0-3 sum, 4-7 sumsq)
        float acc = 0.f;
        #pragma unroll
        for (int k = 0; k < 8; ++k) acc += red[k][j][tq];
        const int ch = tq * 4 + (j & 3);
        atomicAdd(((j < 4) ? sum : sumsq) + seg_first * CC + ch, acc);
        if (threadIdx.x == 0)
            atomicAdd(cnt + seg_first, (float)(rend - r0));
    } else {
        // Boundary block (rare): accumulate per-thread, flush on segment change.
        int cur = -1;
        float rows = 0.f;
        for (int r = r0 + tr; r < rend; r += 8) {
            const int seg = bidx[r];
            if (seg != cur) {
                if (cur >= 0) {
                    float* sd = sum   + cur * CC + tq * 4;
                    float* qd = sumsq + cur * CC + tq * 4;
                    atomicAdd(sd + 0, s0); atomicAdd(sd + 1, s1);
                    atomicAdd(sd + 2, s2); atomicAdd(sd + 3, s3);
                    atomicAdd(qd + 0, q0); atomicAdd(qd + 1, q1);
                    atomicAdd(qd + 2, q2); atomicAdd(qd + 3, q3);
                    if (tq == 0) atomicAdd(cnt + cur, rows);
                    s0 = s1 = s2 = s3 = q0 = q1 = q2 = q3 = 0.f;
                    rows = 0.f;
                }
                cur = seg;
            }
            const float4 v = *reinterpret_cast<const float4*>(x + (size_t)r * CC + tq * 4);
            s0 += v.x; s1 += v.y; s2 += v.z; s3 += v.w;
            q0 += v.x * v.x; q1 += v.y * v.y; q2 += v.z * v.z; q3 += v.w * v.w;
            rows += 1.f;
        }
        if (cur >= 0) {
            float* sd = sum   + cur * CC + tq * 4;
            float* qd = sumsq + cur * CC + tq * 4;
            atomicAdd(sd + 0, s0); atomicAdd(sd + 1, s1);
            atomicAdd(sd + 2, s2); atomicAdd(sd + 3, s3);
            atomicAdd(qd + 0, q0); atomicAdd(qd + 1, q1);
            atomicAdd(qd + 2, q2); atomicAdd(qd + 3, q3);
            if (tq == 0) atomicAdd(cnt + cur, rows);
        }
    }
}

// ---------------------------------------------------------------------------
// Kernel 2: fold stats into per-(segment,channel) scale/shift.
// out = x*scale + shift, scale = instd*w, shift = bias - mean*instd*w.
// var = E[x^2] - mean^2 (== reference's centered two-pass, exact in math).
// ---------------------------------------------------------------------------
__global__ __launch_bounds__(256) void ms_finalize(const float* __restrict__ sum,
                                                   const float* __restrict__ sumsq,
                                                   const float* __restrict__ cnt,
                                                   const float* __restrict__ w,
                                                   const float* __restrict__ bias,
                                                   float* __restrict__ scale,
                                                   float* __restrict__ shift)
{
    const int i = blockIdx.x * blockDim.x + threadIdx.x;
    if (i >= BSEG * CC) return;
    const int b = i / CC;
    const int c = i % CC;
    const float nn = fmaxf(cnt[b], 1.0f);
    const float mean = sum[i] / nn;
    const float var = fmaxf(sumsq[i] / nn - mean * mean, 0.0f);
    const float instd = rsqrtf(var + EPSV);
    const float sc = instd * w[c];
    scale[i] = sc;
    shift[i] = bias[c] - mean * sc;
}

// ---------------------------------------------------------------------------
// Kernel 3: normalize. Grid-stride over N*32 float4 elements; scale/shift
// tables (16 KB) preloaded into LDS per block.
// ---------------------------------------------------------------------------
__global__ __launch_bounds__(256) void ms_norm(const float* __restrict__ x,
                                               const int* __restrict__ bidx,
                                               const float* __restrict__ scale,
                                               const float* __restrict__ shift,
                                               float* __restrict__ out,
                                               int n)
{
    __shared__ float4 s_scale[BSEG * 32];
    __shared__ float4 s_shift[BSEG * 32];
    for (int i = threadIdx.x; i < BSEG * 32; i += blockDim.x) {
        s_scale[i] = reinterpret_cast<const float4*>(scale)[i];
        s_shift[i] = reinterpret_cast<const float4*>(shift)[i];
    }
    __syncthreads();

    const unsigned total = (unsigned)n * 32u;   // N*C/4 float4 units (32M < 2^31)
    const unsigned stride = gridDim.x * blockDim.x;
    for (unsigned idx = blockIdx.x * blockDim.x + threadIdx.x; idx < total; idx += stride) {
        const int r = (int)(idx >> 5);
        const int q = (int)(idx & 31);
        const int seg = bidx[r];
        const float4 v  = reinterpret_cast<const float4*>(x)[idx];
        const float4 sc = s_scale[seg * 32 + q];
        const float4 sh = s_shift[seg * 32 + q];
        float4 o;
        o.x = fmaf(v.x, sc.x, sh.x);
        o.y = fmaf(v.y, sc.y, sh.y);
        o.z = fmaf(v.z, sc.z, sh.z);
        o.w = fmaf(v.w, sc.w, sh.w);
        reinterpret_cast<float4*>(out)[idx] = o;
    }
}

// ---------------------------------------------------------------------------
extern "C" void kernel_launch(void* const* d_in, const int* in_sizes, int n_in,
                              void* d_out, int out_size, void* d_ws, size_t ws_size,
                              hipStream_t stream)
{
    const float* x    = (const float*)d_in[0];
    const int*   bidx = (const int*)d_in[1];
    const float* w    = (const float*)d_in[2];
    const float* bias = (const float*)d_in[3];
    float* out = (float*)d_out;
    const int n = in_sizes[1];   // number of rows (batch_idx length)

    // Workspace layout (floats):
    //   sum[B*C] | sumsq[B*C] | cnt[B] | scale[B*C] | shift[B*C]
    float* ws    = (float*)d_ws;
    float* sum   = ws;
    float* sumsq = ws + BSEG * CC;
    float* cnt   = ws + 2 * BSEG * CC;
    float* scale = ws + 2 * BSEG * CC + BSEG;   // offset 4112 floats (16B aligned)
    float* shift = scale + BSEG * CC;

    // Zero the accumulators (ws is poisoned, and we must be replay-safe).
    hipMemsetAsync(d_ws, 0, (size_t)(2 * BSEG * CC + BSEG) * sizeof(float), stream);

    const int g1 = (n + ROWS_PER_BLOCK - 1) / ROWS_PER_BLOCK;
    ms_stats<<<g1, 256, 0, stream>>>(x, bidx, n, sum, sumsq, cnt);
    ms_finalize<<<(BSEG * CC + 255) / 256, 256, 0, stream>>>(sum, sumsq, cnt, w, bias, scale, shift);
    ms_norm<<<2048, 256, 0, stream>>>(x, bidx, scale, shift, out, n);
}

// Round 3
// 316.484 us; speedup vs baseline: 1.1143x; 1.1143x over previous
//
#include <hip/hip_runtime.h>

#define CC 128          // channels
#define BSEG 16         // segments
#define EPSV 1e-5f
#define ROWS_PER_BLOCK 512

// Native clang vector (unlike HIP's float4 class, valid for
// __builtin_nontemporal_store). Same 16B layout / dwordx4 codegen.
typedef float v4f __attribute__((ext_vector_type(4)));

// ---------------------------------------------------------------------------
// Kernel 1: per-segment per-channel sum / sumsq / count.
// Block owns ROWS_PER_BLOCK contiguous rows. Thread layout: 8 row-lanes x 32
// channel-quads (float4). batch_idx is sorted, so nearly all blocks are
// segment-uniform -> LDS reduce + 256 atomics/block. Boundary blocks (rare)
// take a flush-on-change per-thread atomic path.
// Traversal is FORWARD so the tail of x is the freshest content in L3 when
// the normalize pass starts (it traverses in REVERSE to harvest those hits).
// ---------------------------------------------------------------------------
__global__ __launch_bounds__(256) void ms_stats(const float* __restrict__ x,
                                                const int* __restrict__ bidx,
                                                int n,
                                                float* __restrict__ sum,
                                                float* __restrict__ sumsq,
                                                float* __restrict__ cnt)
{
    const int r0 = blockIdx.x * ROWS_PER_BLOCK;
    if (r0 >= n) return;
    const int rend = min(r0 + ROWS_PER_BLOCK, n);
    const int tq = threadIdx.x & 31;   // channel quad 0..31 -> channels 4*tq..4*tq+3
    const int tr = threadIdx.x >> 5;   // row lane 0..7

    const int seg_first = bidx[r0];
    const int seg_last  = bidx[rend - 1];

    float s0 = 0.f, s1 = 0.f, s2 = 0.f, s3 = 0.f;
    float q0 = 0.f, q1 = 0.f, q2 = 0.f, q3 = 0.f;

    if (seg_first == seg_last) {
        // Uniform block (common case).
        for (int r = r0 + tr; r < rend; r += 8) {
            const v4f v = *reinterpret_cast<const v4f*>(x + (size_t)r * CC + tq * 4);
            s0 += v.x; s1 += v.y; s2 += v.z; s3 += v.w;
            q0 += v.x * v.x; q1 += v.y * v.y; q2 += v.z * v.z; q3 += v.w * v.w;
        }
        // Reduce the 8 row-lanes in LDS. Layout [tr][slot][tq]: lane-consecutive
        // on both write and read -> conflict-free.
        __shared__ float red[8][8][32];
        red[tr][0][tq] = s0; red[tr][1][tq] = s1; red[tr][2][tq] = s2; red[tr][3][tq] = s3;
        red[tr][4][tq] = q0; red[tr][5][tq] = q1; red[tr][6][tq] = q2; red[tr][7][tq] = q3;
        __syncthreads();
        const int j = threadIdx.x >> 5;   // slot 0..7 (0-3 sum, 4-7 sumsq)
        float acc = 0.f;
        #pragma unroll
        for (int k = 0; k < 8; ++k) acc += red[k][j][tq];
        const int ch = tq * 4 + (j & 3);
        atomicAdd(((j < 4) ? sum : sumsq) + seg_first * CC + ch, acc);
        if (threadIdx.x == 0)
            atomicAdd(cnt + seg_first, (float)(rend - r0));
    } else {
        // Boundary block (rare): accumulate per-thread, flush on segment change.
        int cur = -1;
        float rows = 0.f;
        for (int r = r0 + tr; r < rend; r += 8) {
            const int seg = bidx[r];
            if (seg != cur) {
                if (cur >= 0) {
                    float* sd = sum   + cur * CC + tq * 4;
                    float* qd = sumsq + cur * CC + tq * 4;
                    atomicAdd(sd + 0, s0); atomicAdd(sd + 1, s1);
                    atomicAdd(sd + 2, s2); atomicAdd(sd + 3, s3);
                    atomicAdd(qd + 0, q0); atomicAdd(qd + 1, q1);
                    atomicAdd(qd + 2, q2); atomicAdd(qd + 3, q3);
                    if (tq == 0) atomicAdd(cnt + cur, rows);
                    s0 = s1 = s2 = s3 = q0 = q1 = q2 = q3 = 0.f;
                    rows = 0.f;
                }
                cur = seg;
            }
            const v4f v = *reinterpret_cast<const v4f*>(x + (size_t)r * CC + tq * 4);
            s0 += v.x; s1 += v.y; s2 += v.z; s3 += v.w;
            q0 += v.x * v.x; q1 += v.y * v.y; q2 += v.z * v.z; q3 += v.w * v.w;
            rows += 1.f;
        }
        if (cur >= 0) {
            float* sd = sum   + cur * CC + tq * 4;
            float* qd = sumsq + cur * CC + tq * 4;
            atomicAdd(sd + 0, s0); atomicAdd(sd + 1, s1);
            atomicAdd(sd + 2, s2); atomicAdd(sd + 3, s3);
            atomicAdd(qd + 0, q0); atomicAdd(qd + 1, q1);
            atomicAdd(qd + 2, q2); atomicAdd(qd + 3, q3);
            if (tq == 0) atomicAdd(cnt + cur, rows);
        }
    }
}

// ---------------------------------------------------------------------------
// Kernel 2: normalize (finalize fused into the LDS-preload phase).
// Each block computes the full [B][C] scale/shift table into LDS (8 rsqrt per
// thread, global inputs are L2-hot after the first blocks), then grid-strides
// the N*32 float4 elements in REVERSE order: the tail of x was streamed into
// L3 most recently by ms_stats, so reading it back high->low harvests L3 hits.
// out is written with nontemporal stores so the 512 MB of output doesn't
// evict x's resident tail from L3 mid-pass.
// ---------------------------------------------------------------------------
__global__ __launch_bounds__(256) void ms_norm(const float* __restrict__ x,
                                               const int* __restrict__ bidx,
                                               const float* __restrict__ sum,
                                               const float* __restrict__ sumsq,
                                               const float* __restrict__ cnt,
                                               const float* __restrict__ w,
                                               const float* __restrict__ bias,
                                               float* __restrict__ out,
                                               int n)
{
    __shared__ float s_scale[BSEG * CC];
    __shared__ float s_shift[BSEG * CC];
    for (int i = threadIdx.x; i < BSEG * CC; i += 256) {
        const int b = i >> 7;          // CC == 128
        const int c = i & (CC - 1);
        const float nn   = fmaxf(cnt[b], 1.0f);
        const float mean = sum[i] / nn;
        const float var  = fmaxf(sumsq[i] / nn - mean * mean, 0.0f);
        const float sc   = rsqrtf(var + EPSV) * w[c];
        s_scale[i] = sc;
        s_shift[i] = fmaf(-mean, sc, bias[c]);
    }
    __syncthreads();

    const unsigned total  = (unsigned)n * 32u;   // N*C/4 float4 units (32M < 2^31)
    const unsigned stride = gridDim.x * blockDim.x;
    for (unsigned i = blockIdx.x * blockDim.x + threadIdx.x; i < total; i += stride) {
        const unsigned idx = total - 1u - i;     // reverse traversal for L3 reuse
        const int r = (int)(idx >> 5);
        const int q = (int)(idx & 31);
        const int seg  = bidx[r];
        const int base = seg * CC + q * 4;
        const v4f v = reinterpret_cast<const v4f*>(x)[idx];
        v4f o;
        o.x = fmaf(v.x, s_scale[base + 0], s_shift[base + 0]);
        o.y = fmaf(v.y, s_scale[base + 1], s_shift[base + 1]);
        o.z = fmaf(v.z, s_scale[base + 2], s_shift[base + 2]);
        o.w = fmaf(v.w, s_scale[base + 3], s_shift[base + 3]);
        __builtin_nontemporal_store(o, reinterpret_cast<v4f*>(out) + idx);
    }
}

// ---------------------------------------------------------------------------
extern "C" void kernel_launch(void* const* d_in, const int* in_sizes, int n_in,
                              void* d_out, int out_size, void* d_ws, size_t ws_size,
                              hipStream_t stream)
{
    const float* x    = (const float*)d_in[0];
    const int*   bidx = (const int*)d_in[1];
    const float* w    = (const float*)d_in[2];
    const float* bias = (const float*)d_in[3];
    float* out = (float*)d_out;
    const int n = in_sizes[1];   // number of rows (batch_idx length)

    // Workspace layout (floats): sum[B*C] | sumsq[B*C] | cnt[B]
    float* ws    = (float*)d_ws;
    float* sum   = ws;
    float* sumsq = ws + BSEG * CC;
    float* cnt   = ws + 2 * BSEG * CC;

    // Zero the accumulators (ws is poisoned, and we must be replay-safe).
    (void)hipMemsetAsync(d_ws, 0, (size_t)(2 * BSEG * CC + BSEG) * sizeof(float), stream);

    const int g1 = (n + ROWS_PER_BLOCK - 1) / ROWS_PER_BLOCK;
    ms_stats<<<g1, 256, 0, stream>>>(x, bidx, n, sum, sumsq, cnt);
    ms_norm<<<2048, 256, 0, stream>>>(x, bidx, sum, sumsq, cnt, w, bias, out, n);
}